// Round 1
// baseline (667.735 us; speedup 1.0000x reference)
//
#include <hip/hip_runtime.h>
#include <hip/hip_bf16.h>

#define NNODES 50000
#define NEDGES 800000
#define NDIM   128
#define EDIM   64
#define K1     192   // NDIM + EDIM
#define K2     256   // 2*NDIM

#define KP1 200      // LDS k-stride for K=192 (100 dwords, %32==4 -> 2-way only)
#define KPA 136      // LDS k-stride for K=128
#define KPU 264      // LDS k-stride for K=256

typedef __attribute__((ext_vector_type(8))) short bf16x8;
typedef __attribute__((ext_vector_type(4))) short bf16x4;
typedef __attribute__((ext_vector_type(4))) float f32x4;

__device__ inline short f2bf(float f) {
  union { float f; unsigned u; } v; v.f = f;
  unsigned r = v.u + 0x7FFFu + ((v.u >> 16) & 1u);   // round-to-nearest-even
  return (short)(r >> 16);
}

__device__ inline bf16x4 pack4(float4 v) {
  bf16x4 p;
  p[0] = f2bf(v.x); p[1] = f2bf(v.y); p[2] = f2bf(v.z); p[3] = f2bf(v.w);
  return p;
}

// Transpose+convert fp32 weight [K][128] -> bf16 [n][K] (k contiguous per output col)
__global__ __launch_bounds__(256) void wt_kernel(const float* __restrict__ w,
                                                 short* __restrict__ wt, int K) {
  int i = blockIdx.x * 256 + threadIdx.x;
  if (i < K * NDIM) {
    int k = i >> 7;          // /128
    int n = i & 127;
    wt[n * K + k] = f2bf(w[i]);
  }
}

// Edge kernel: h = lrelu(concat(node[dst], edge)@W1 + b1); hagg[src] += h; deg[src] += 1
__global__ __launch_bounds__(256) void edge_kernel(const float* __restrict__ node_feats,
                                                   const float* __restrict__ edge_feats,
                                                   const int* __restrict__ eidx,
                                                   const short* __restrict__ w1t,
                                                   const float* __restrict__ b1,
                                                   float* __restrict__ hagg,
                                                   float* __restrict__ deg) {
  __shared__ __align__(16) short X[64 * KP1];
  __shared__ int srcs[64];
  __shared__ int dsts[64];

  const int tid = threadIdx.x;
  const int e0 = blockIdx.x * 64;

  if (tid < 64) {
    int s = eidx[e0 + tid];
    int d = eidx[NEDGES + e0 + tid];
    srcs[tid] = s;
    dsts[tid] = d;
    atomicAdd(&deg[s], 1.0f);
  }
  __syncthreads();

  // Stage node[dst] part: 4 threads per row, each covers 32 cols
  {
    int r = tid >> 2, q = tid & 3;
    const float4* np = (const float4*)(node_feats + (size_t)dsts[r] * NDIM) + q * 8;
    short* dp = X + r * KP1 + q * 32;
#pragma unroll
    for (int j = 0; j < 8; ++j) {
      *(bf16x4*)(dp + j * 4) = pack4(np[j]);
    }
  }
  // Stage edge_feats part: fully coalesced (tile rows are consecutive edges)
  {
    const float4* ef = (const float4*)(edge_feats + (size_t)e0 * EDIM);
#pragma unroll
    for (int j = 0; j < 4; ++j) {
      int f = tid + 256 * j;          // 0..1023 float4s = 64 rows x 16 float4
      int r = f >> 4, c4 = f & 15;
      *(bf16x4*)(X + r * KP1 + NDIM + c4 * 4) = pack4(ef[f]);
    }
  }
  __syncthreads();

  const int lane = tid & 63;
  const int wv = tid >> 6;          // wave handles cols [wv*32, wv*32+32)
  const int m16 = lane & 15;
  const int quad = lane >> 4;

  f32x4 acc[4][2];
#pragma unroll
  for (int mt = 0; mt < 4; ++mt)
#pragma unroll
    for (int nt = 0; nt < 2; ++nt)
      acc[mt][nt] = (f32x4){0.f, 0.f, 0.f, 0.f};

#pragma unroll
  for (int ks = 0; ks < 6; ++ks) {
    const int k0 = ks * 32 + quad * 8;
    bf16x8 b[2];
#pragma unroll
    for (int nt = 0; nt < 2; ++nt) {
      int n = wv * 32 + nt * 16 + m16;
      b[nt] = *(const bf16x8*)(w1t + n * K1 + k0);     // L2-resident
    }
#pragma unroll
    for (int mt = 0; mt < 4; ++mt) {
      bf16x8 a = *(const bf16x8*)(X + (mt * 16 + m16) * KP1 + k0);
#pragma unroll
      for (int nt = 0; nt < 2; ++nt)
        acc[mt][nt] = __builtin_amdgcn_mfma_f32_16x16x32_bf16(a, b[nt], acc[mt][nt], 0, 0, 0);
    }
  }

  // Epilogue: bias + leaky_relu + fp32 atomic scatter of h into hagg[src]
#pragma unroll
  for (int nt = 0; nt < 2; ++nt) {
    int col = wv * 32 + nt * 16 + m16;
    float bias = b1[col];
#pragma unroll
    for (int mt = 0; mt < 4; ++mt) {
#pragma unroll
      for (int i = 0; i < 4; ++i) {
        float v = acc[mt][nt][i] + bias;
        v = v >= 0.f ? v : 0.2f * v;
        int row = mt * 16 + quad * 4 + i;
        atomicAdd(&hagg[(size_t)srcs[row] * NDIM + col], v);
      }
    }
  }
}

// Node kernel: agg = hagg@W2 + deg*b2; out = lrelu(concat(x,agg)@U1+ub1)@U2+ub2
__global__ __launch_bounds__(256) void node_kernel(const float* __restrict__ node_feats,
                                                   const float* __restrict__ hagg,
                                                   const float* __restrict__ deg,
                                                   const short* __restrict__ w2t,
                                                   const float* __restrict__ b2,
                                                   const short* __restrict__ u1t,
                                                   const float* __restrict__ ub1,
                                                   const short* __restrict__ u2t,
                                                   const float* __restrict__ ub2,
                                                   float* __restrict__ out) {
  __shared__ __align__(16) short AGH[64 * KPA];   // phase1: hagg tile; phase3: h2 tile
  __shared__ __align__(16) short XU[64 * KPU];    // concat(x, agg) tile
  __shared__ float degs[64];

  const int tid = threadIdx.x;
  const int n0 = blockIdx.x * 64;

  if (tid < 64) {
    int node = n0 + tid;
    degs[tid] = (node < NNODES) ? deg[node] : 0.f;
  }
  // Stage hagg -> AGH and node_feats -> XU[:,0:128]
  {
    int r = tid >> 2, q = tid & 3;
    int node = n0 + r; if (node >= NNODES) node = NNODES - 1;
    const float4* hp = (const float4*)(hagg + (size_t)node * NDIM) + q * 8;
    const float4* xp = (const float4*)(node_feats + (size_t)node * NDIM) + q * 8;
    short* ap = AGH + r * KPA + q * 32;
    short* xq = XU + r * KPU + q * 32;
#pragma unroll
    for (int j = 0; j < 8; ++j) {
      *(bf16x4*)(ap + j * 4) = pack4(hp[j]);
      *(bf16x4*)(xq + j * 4) = pack4(xp[j]);
    }
  }
  __syncthreads();

  const int lane = tid & 63;
  const int wv = tid >> 6;
  const int m16 = lane & 15;
  const int quad = lane >> 4;

  f32x4 acc[4][2];

  // ---- GEMM-a: agg = AGH @ W2 (K=128) ----
#pragma unroll
  for (int mt = 0; mt < 4; ++mt)
#pragma unroll
    for (int nt = 0; nt < 2; ++nt)
      acc[mt][nt] = (f32x4){0.f, 0.f, 0.f, 0.f};
#pragma unroll
  for (int ks = 0; ks < 4; ++ks) {
    const int k0 = ks * 32 + quad * 8;
    bf16x8 b[2];
#pragma unroll
    for (int nt = 0; nt < 2; ++nt) {
      int n = wv * 32 + nt * 16 + m16;
      b[nt] = *(const bf16x8*)(w2t + n * NDIM + k0);
    }
#pragma unroll
    for (int mt = 0; mt < 4; ++mt) {
      bf16x8 a = *(const bf16x8*)(AGH + (mt * 16 + m16) * KPA + k0);
#pragma unroll
      for (int nt = 0; nt < 2; ++nt)
        acc[mt][nt] = __builtin_amdgcn_mfma_f32_16x16x32_bf16(a, b[nt], acc[mt][nt], 0, 0, 0);
    }
  }
  // epilogue: + deg*b2, write bf16 into XU[:,128:256]
#pragma unroll
  for (int nt = 0; nt < 2; ++nt) {
    int col = wv * 32 + nt * 16 + m16;
    float bb = b2[col];
#pragma unroll
    for (int mt = 0; mt < 4; ++mt) {
#pragma unroll
      for (int i = 0; i < 4; ++i) {
        int row = mt * 16 + quad * 4 + i;
        float v = acc[mt][nt][i] + degs[row] * bb;
        XU[row * KPU + NDIM + col] = f2bf(v);
      }
    }
  }
  __syncthreads();

  // ---- GEMM-b: t = XU @ U1 (K=256), lrelu -> AGH (reused as h2) ----
#pragma unroll
  for (int mt = 0; mt < 4; ++mt)
#pragma unroll
    for (int nt = 0; nt < 2; ++nt)
      acc[mt][nt] = (f32x4){0.f, 0.f, 0.f, 0.f};
#pragma unroll
  for (int ks = 0; ks < 8; ++ks) {
    const int k0 = ks * 32 + quad * 8;
    bf16x8 b[2];
#pragma unroll
    for (int nt = 0; nt < 2; ++nt) {
      int n = wv * 32 + nt * 16 + m16;
      b[nt] = *(const bf16x8*)(u1t + n * K2 + k0);
    }
#pragma unroll
    for (int mt = 0; mt < 4; ++mt) {
      bf16x8 a = *(const bf16x8*)(XU + (mt * 16 + m16) * KPU + k0);
#pragma unroll
      for (int nt = 0; nt < 2; ++nt)
        acc[mt][nt] = __builtin_amdgcn_mfma_f32_16x16x32_bf16(a, b[nt], acc[mt][nt], 0, 0, 0);
    }
  }
  __syncthreads();   // all GEMM-b A-reads done before overwriting AGH
#pragma unroll
  for (int nt = 0; nt < 2; ++nt) {
    int col = wv * 32 + nt * 16 + m16;
    float bb = ub1[col];
#pragma unroll
    for (int mt = 0; mt < 4; ++mt) {
#pragma unroll
      for (int i = 0; i < 4; ++i) {
        int row = mt * 16 + quad * 4 + i;
        float v = acc[mt][nt][i] + bb;
        v = v >= 0.f ? v : 0.2f * v;
        AGH[row * KPA + col] = f2bf(v);
      }
    }
  }
  __syncthreads();

  // ---- GEMM-c: out = h2 @ U2 (K=128) + ub2 ----
#pragma unroll
  for (int mt = 0; mt < 4; ++mt)
#pragma unroll
    for (int nt = 0; nt < 2; ++nt)
      acc[mt][nt] = (f32x4){0.f, 0.f, 0.f, 0.f};
#pragma unroll
  for (int ks = 0; ks < 4; ++ks) {
    const int k0 = ks * 32 + quad * 8;
    bf16x8 b[2];
#pragma unroll
    for (int nt = 0; nt < 2; ++nt) {
      int n = wv * 32 + nt * 16 + m16;
      b[nt] = *(const bf16x8*)(u2t + n * NDIM + k0);
    }
#pragma unroll
    for (int mt = 0; mt < 4; ++mt) {
      bf16x8 a = *(const bf16x8*)(AGH + (mt * 16 + m16) * KPA + k0);
#pragma unroll
      for (int nt = 0; nt < 2; ++nt)
        acc[mt][nt] = __builtin_amdgcn_mfma_f32_16x16x32_bf16(a, b[nt], acc[mt][nt], 0, 0, 0);
    }
  }
#pragma unroll
  for (int nt = 0; nt < 2; ++nt) {
    int col = wv * 32 + nt * 16 + m16;
    float bb = ub2[col];
#pragma unroll
    for (int mt = 0; mt < 4; ++mt) {
#pragma unroll
      for (int i = 0; i < 4; ++i) {
        int row = mt * 16 + quad * 4 + i;
        int node = n0 + row;
        if (node < NNODES)
          out[(size_t)node * NDIM + col] = acc[mt][nt][i] + bb;
      }
    }
  }
}

extern "C" void kernel_launch(void* const* d_in, const int* in_sizes, int n_in,
                              void* d_out, int out_size, void* d_ws, size_t ws_size,
                              hipStream_t stream) {
  const float* node_feats = (const float*)d_in[0];
  const float* edge_feats = (const float*)d_in[1];
  const float* msg_w1 = (const float*)d_in[2];
  const float* msg_b1 = (const float*)d_in[3];
  const float* msg_w2 = (const float*)d_in[4];
  const float* msg_b2 = (const float*)d_in[5];
  const float* upd_w1 = (const float*)d_in[6];
  const float* upd_b1 = (const float*)d_in[7];
  const float* upd_w2 = (const float*)d_in[8];
  const float* upd_b2 = (const float*)d_in[9];
  const int* eidx = (const int*)d_in[10];

  float* hagg = (float*)d_ws;                          // N*128 f32
  float* deg = hagg + (size_t)NNODES * NDIM;           // N f32
  short* w1t = (short*)(deg + NNODES);                 // 128*192 bf16 (16B aligned)
  short* w2t = w1t + 128 * K1;
  short* u1t = w2t + 128 * 128;
  short* u2t = u1t + 128 * K2;

  hipMemsetAsync(d_ws, 0, (size_t)(NNODES * NDIM + NNODES) * sizeof(float), stream);

  wt_kernel<<<(K1 * 128) / 256, 256, 0, stream>>>(msg_w1, w1t, K1);
  wt_kernel<<<(128 * 128) / 256, 256, 0, stream>>>(msg_w2, w2t, 128);
  wt_kernel<<<(K2 * 128) / 256, 256, 0, stream>>>(upd_w1, u1t, K2);
  wt_kernel<<<(128 * 128) / 256, 256, 0, stream>>>(upd_w2, u2t, 128);

  edge_kernel<<<NEDGES / 64, 256, 0, stream>>>(node_feats, edge_feats, eidx,
                                               w1t, msg_b1, hagg, deg);
  node_kernel<<<(NNODES + 63) / 64, 256, 0, stream>>>(node_feats, hagg, deg,
                                                      w2t, msg_b2, u1t, upd_b1,
                                                      u2t, upd_b2, (float*)d_out);
}

// Round 2
// 564.623 us; speedup vs baseline: 1.1826x; 1.1826x over previous
//
#include <hip/hip_runtime.h>
#include <hip/hip_bf16.h>

#define NNODES 50000
#define NEDGES 800000
#define NDIM   128
#define EDIM   64
#define K1     192   // NDIM + EDIM
#define K2     256   // 2*NDIM
#define NB     196   // ceil(NNODES/256) scan blocks

#define KP1 200      // LDS k-stride (shorts) for K=192 tile
#define KPA 136      // LDS k-stride for K=128
#define KPU 264      // LDS k-stride for K=256
#define MSTR 132     // LDS col-stride (floats) for message tile

typedef __attribute__((ext_vector_type(8))) short bf16x8;
typedef __attribute__((ext_vector_type(4))) short bf16x4;
typedef __attribute__((ext_vector_type(4))) float f32x4;

__device__ inline short f2bf(float f) {
  union { float f; unsigned u; } v; v.f = f;
  unsigned r = v.u + 0x7FFFu + ((v.u >> 16) & 1u);   // round-to-nearest-even
  return (short)(r >> 16);
}

__device__ inline bf16x4 pack4(float4 v) {
  bf16x4 p;
  p[0] = f2bf(v.x); p[1] = f2bf(v.y); p[2] = f2bf(v.z); p[3] = f2bf(v.w);
  return p;
}

// Transpose+convert fp32 weight [K][128] -> bf16 [n][K]
__global__ __launch_bounds__(256) void wt_kernel(const float* __restrict__ w,
                                                 short* __restrict__ wt, int K) {
  int i = blockIdx.x * 256 + threadIdx.x;
  if (i < K * NDIM) {
    int k = i >> 7;
    int n = i & 127;
    wt[n * K + k] = f2bf(w[i]);
  }
}

// ---- counting-sort pipeline: sort edges by src ----
__global__ __launch_bounds__(256) void hist_kernel(const int* __restrict__ eidx,
                                                   int* __restrict__ cnt) {
  int i = blockIdx.x * 256 + threadIdx.x;
  if (i < NEDGES) atomicAdd(&cnt[eidx[i]], 1);
}

__global__ __launch_bounds__(256) void scan_reduce_kernel(const int* __restrict__ cnt,
                                                          int* __restrict__ bsum) {
  __shared__ int sh[256];
  int tid = threadIdx.x;
  int i = blockIdx.x * 256 + tid;
  sh[tid] = (i < NNODES) ? cnt[i] : 0;
  __syncthreads();
#pragma unroll
  for (int off = 128; off > 0; off >>= 1) {
    if (tid < off) sh[tid] += sh[tid + off];
    __syncthreads();
  }
  if (tid == 0) bsum[blockIdx.x] = sh[0];
}

__global__ __launch_bounds__(256) void scan_top_kernel(const int* __restrict__ bsum,
                                                       int* __restrict__ bscan) {
  __shared__ int sh[256];
  int tid = threadIdx.x;
  int v = (tid < NB) ? bsum[tid] : 0;
  sh[tid] = v;
  __syncthreads();
#pragma unroll
  for (int off = 1; off < 256; off <<= 1) {
    int t = (tid >= off) ? sh[tid - off] : 0;
    __syncthreads();
    sh[tid] += t;
    __syncthreads();
  }
  bscan[tid] = sh[tid] - v;   // exclusive
}

__global__ __launch_bounds__(256) void scan_down_kernel(int* __restrict__ cnt,
                                                        const int* __restrict__ bscan,
                                                        int* __restrict__ row_ptr) {
  __shared__ int sh[256];
  int tid = threadIdx.x;
  int i = blockIdx.x * 256 + tid;
  int v = (i < NNODES) ? cnt[i] : 0;
  sh[tid] = v;
  __syncthreads();
#pragma unroll
  for (int off = 1; off < 256; off <<= 1) {
    int t = (tid >= off) ? sh[tid - off] : 0;
    __syncthreads();
    sh[tid] += t;
    __syncthreads();
  }
  if (i < NNODES) {
    row_ptr[i] = bscan[blockIdx.x] + (sh[tid] - v);
    cnt[i] = 0;                 // reset: becomes the ticket counter for permute
  }
}

__global__ __launch_bounds__(256) void permute_kernel(const int* __restrict__ eidx,
                                                      const int* __restrict__ row_ptr,
                                                      int* __restrict__ cnt,
                                                      int4* __restrict__ s_edges) {
  int e = blockIdx.x * 256 + threadIdx.x;
  if (e < NEDGES) {
    int s = eidx[e];
    int d = eidx[NEDGES + e];
    int pos = row_ptr[s] + atomicAdd(&cnt[s], 1);   // cnt ends equal to degree
    s_edges[pos] = make_int4(s, d, e, 0);
  }
}

// ---- edge kernel: h = lrelu(concat(node[dst], edge)@W1 + b1);
//      tile-local run aggregation over sorted src, then atomicAdd per run ----
__global__ __launch_bounds__(256) void edge_kernel(const float* __restrict__ node_feats,
                                                   const float* __restrict__ edge_feats,
                                                   const int4* __restrict__ s_edges,
                                                   const short* __restrict__ w1t,
                                                   const float* __restrict__ b1,
                                                   float* __restrict__ hagg) {
  __shared__ __align__(16) char SH[64 * MSTR * 4];   // 33792 B: aliases X (25600 B) then M
  __shared__ int srcs[64];
  __shared__ int dsts[64];
  __shared__ int eids[64];

  short* X = (short*)SH;     // bf16 [64][KP1] input tile
  float* M = (float*)SH;     // fp32 [64][MSTR] message tile (after X is dead)

  const int tid = threadIdx.x;
  const int e0 = blockIdx.x * 64;

  if (tid < 64) {
    int4 v = s_edges[e0 + tid];
    srcs[tid] = v.x;
    dsts[tid] = v.y;
    eids[tid] = v.z;
  }
  __syncthreads();

  // Stage: 4 threads per row; node[dst] -> cols 0:128, edge_feats[eid] -> cols 128:192
  {
    int r = tid >> 2, q = tid & 3;
    const float4* np = (const float4*)(node_feats + (size_t)dsts[r] * NDIM) + q * 8;
    const float4* ep = (const float4*)(edge_feats + (size_t)eids[r] * EDIM) + q * 4;
    short* dpn = X + r * KP1 + q * 32;
    short* dpe = X + r * KP1 + NDIM + q * 16;
#pragma unroll
    for (int j = 0; j < 8; ++j) *(bf16x4*)(dpn + j * 4) = pack4(np[j]);
#pragma unroll
    for (int j = 0; j < 4; ++j) *(bf16x4*)(dpe + j * 4) = pack4(ep[j]);
  }
  __syncthreads();

  const int lane = tid & 63;
  const int wv = tid >> 6;
  const int m16 = lane & 15;
  const int quad = lane >> 4;

  f32x4 acc[4][2];
#pragma unroll
  for (int mt = 0; mt < 4; ++mt)
#pragma unroll
    for (int nt = 0; nt < 2; ++nt)
      acc[mt][nt] = (f32x4){0.f, 0.f, 0.f, 0.f};

#pragma unroll
  for (int ks = 0; ks < 6; ++ks) {
    const int k0 = ks * 32 + quad * 8;
    bf16x8 b[2];
#pragma unroll
    for (int nt = 0; nt < 2; ++nt) {
      int n = wv * 32 + nt * 16 + m16;
      b[nt] = *(const bf16x8*)(w1t + n * K1 + k0);
    }
#pragma unroll
    for (int mt = 0; mt < 4; ++mt) {
      bf16x8 a = *(const bf16x8*)(X + (mt * 16 + m16) * KP1 + k0);
#pragma unroll
      for (int nt = 0; nt < 2; ++nt)
        acc[mt][nt] = __builtin_amdgcn_mfma_f32_16x16x32_bf16(a, b[nt], acc[mt][nt], 0, 0, 0);
    }
  }
  __syncthreads();   // all X reads done before M overwrites it

  // bias + leaky_relu -> LDS message tile
#pragma unroll
  for (int nt = 0; nt < 2; ++nt) {
    int col = wv * 32 + nt * 16 + m16;
    float bias = b1[col];
#pragma unroll
    for (int mt = 0; mt < 4; ++mt) {
#pragma unroll
      for (int i = 0; i < 4; ++i) {
        float v = acc[mt][nt][i] + bias;
        v = v >= 0.f ? v : 0.2f * v;
        int row = mt * 16 + quad * 4 + i;
        M[row * MSTR + col] = v;
      }
    }
  }
  __syncthreads();

  // run-aggregated scatter: srcs sorted within tile -> one atomic per (run,col)
  if (tid < 128) {
    const int c = tid;
    float a = M[c];          // row 0
    int prev = srcs[0];
#pragma unroll 4
    for (int r = 1; r < 64; ++r) {
      int s = srcs[r];
      float v = M[r * MSTR + c];
      if (s != prev) {
        atomicAdd(&hagg[(size_t)prev * NDIM + c], a);
        a = v;
        prev = s;
      } else {
        a += v;
      }
    }
    atomicAdd(&hagg[(size_t)prev * NDIM + c], a);
  }
}

// ---- node kernel: agg = hagg@W2 + deg*b2; out = lrelu(concat(x,agg)@U1+ub1)@U2+ub2 ----
__global__ __launch_bounds__(256) void node_kernel(const float* __restrict__ node_feats,
                                                   const float* __restrict__ hagg,
                                                   const int* __restrict__ degc,
                                                   const short* __restrict__ w2t,
                                                   const float* __restrict__ b2,
                                                   const short* __restrict__ u1t,
                                                   const float* __restrict__ ub1,
                                                   const short* __restrict__ u2t,
                                                   const float* __restrict__ ub2,
                                                   float* __restrict__ out) {
  __shared__ __align__(16) short AGH[64 * KPA];   // phase1: hagg tile; phase3: h2 tile
  __shared__ __align__(16) short XU[64 * KPU];    // concat(x, agg) tile
  __shared__ float degs[64];

  const int tid = threadIdx.x;
  const int n0 = blockIdx.x * 64;

  if (tid < 64) {
    int node = n0 + tid;
    degs[tid] = (node < NNODES) ? (float)degc[node] : 0.f;
  }
  {
    int r = tid >> 2, q = tid & 3;
    int node = n0 + r; if (node >= NNODES) node = NNODES - 1;
    const float4* hp = (const float4*)(hagg + (size_t)node * NDIM) + q * 8;
    const float4* xp = (const float4*)(node_feats + (size_t)node * NDIM) + q * 8;
    short* ap = AGH + r * KPA + q * 32;
    short* xq = XU + r * KPU + q * 32;
#pragma unroll
    for (int j = 0; j < 8; ++j) {
      *(bf16x4*)(ap + j * 4) = pack4(hp[j]);
      *(bf16x4*)(xq + j * 4) = pack4(xp[j]);
    }
  }
  __syncthreads();

  const int lane = tid & 63;
  const int wv = tid >> 6;
  const int m16 = lane & 15;
  const int quad = lane >> 4;

  f32x4 acc[4][2];

  // ---- GEMM-a: agg = AGH @ W2 (K=128) ----
#pragma unroll
  for (int mt = 0; mt < 4; ++mt)
#pragma unroll
    for (int nt = 0; nt < 2; ++nt)
      acc[mt][nt] = (f32x4){0.f, 0.f, 0.f, 0.f};
#pragma unroll
  for (int ks = 0; ks < 4; ++ks) {
    const int k0 = ks * 32 + quad * 8;
    bf16x8 b[2];
#pragma unroll
    for (int nt = 0; nt < 2; ++nt) {
      int n = wv * 32 + nt * 16 + m16;
      b[nt] = *(const bf16x8*)(w2t + n * NDIM + k0);
    }
#pragma unroll
    for (int mt = 0; mt < 4; ++mt) {
      bf16x8 a = *(const bf16x8*)(AGH + (mt * 16 + m16) * KPA + k0);
#pragma unroll
      for (int nt = 0; nt < 2; ++nt)
        acc[mt][nt] = __builtin_amdgcn_mfma_f32_16x16x32_bf16(a, b[nt], acc[mt][nt], 0, 0, 0);
    }
  }
#pragma unroll
  for (int nt = 0; nt < 2; ++nt) {
    int col = wv * 32 + nt * 16 + m16;
    float bb = b2[col];
#pragma unroll
    for (int mt = 0; mt < 4; ++mt) {
#pragma unroll
      for (int i = 0; i < 4; ++i) {
        int row = mt * 16 + quad * 4 + i;
        float v = acc[mt][nt][i] + degs[row] * bb;
        XU[row * KPU + NDIM + col] = f2bf(v);
      }
    }
  }
  __syncthreads();

  // ---- GEMM-b: t = XU @ U1 (K=256), lrelu -> AGH ----
#pragma unroll
  for (int mt = 0; mt < 4; ++mt)
#pragma unroll
    for (int nt = 0; nt < 2; ++nt)
      acc[mt][nt] = (f32x4){0.f, 0.f, 0.f, 0.f};
#pragma unroll
  for (int ks = 0; ks < 8; ++ks) {
    const int k0 = ks * 32 + quad * 8;
    bf16x8 b[2];
#pragma unroll
    for (int nt = 0; nt < 2; ++nt) {
      int n = wv * 32 + nt * 16 + m16;
      b[nt] = *(const bf16x8*)(u1t + n * K2 + k0);
    }
#pragma unroll
    for (int mt = 0; mt < 4; ++mt) {
      bf16x8 a = *(const bf16x8*)(XU + (mt * 16 + m16) * KPU + k0);
#pragma unroll
      for (int nt = 0; nt < 2; ++nt)
        acc[mt][nt] = __builtin_amdgcn_mfma_f32_16x16x32_bf16(a, b[nt], acc[mt][nt], 0, 0, 0);
    }
  }
  __syncthreads();
#pragma unroll
  for (int nt = 0; nt < 2; ++nt) {
    int col = wv * 32 + nt * 16 + m16;
    float bb = ub1[col];
#pragma unroll
    for (int mt = 0; mt < 4; ++mt) {
#pragma unroll
      for (int i = 0; i < 4; ++i) {
        int row = mt * 16 + quad * 4 + i;
        float v = acc[mt][nt][i] + bb;
        v = v >= 0.f ? v : 0.2f * v;
        AGH[row * KPA + col] = f2bf(v);
      }
    }
  }
  __syncthreads();

  // ---- GEMM-c: out = h2 @ U2 (K=128) + ub2 ----
#pragma unroll
  for (int mt = 0; mt < 4; ++mt)
#pragma unroll
    for (int nt = 0; nt < 2; ++nt)
      acc[mt][nt] = (f32x4){0.f, 0.f, 0.f, 0.f};
#pragma unroll
  for (int ks = 0; ks < 4; ++ks) {
    const int k0 = ks * 32 + quad * 8;
    bf16x8 b[2];
#pragma unroll
    for (int nt = 0; nt < 2; ++nt) {
      int n = wv * 32 + nt * 16 + m16;
      b[nt] = *(const bf16x8*)(u2t + n * NDIM + k0);
    }
#pragma unroll
    for (int mt = 0; mt < 4; ++mt) {
      bf16x8 a = *(const bf16x8*)(AGH + (mt * 16 + m16) * KPA + k0);
#pragma unroll
      for (int nt = 0; nt < 2; ++nt)
        acc[mt][nt] = __builtin_amdgcn_mfma_f32_16x16x32_bf16(a, b[nt], acc[mt][nt], 0, 0, 0);
    }
  }
#pragma unroll
  for (int nt = 0; nt < 2; ++nt) {
    int col = wv * 32 + nt * 16 + m16;
    float bb = ub2[col];
#pragma unroll
    for (int mt = 0; mt < 4; ++mt) {
#pragma unroll
      for (int i = 0; i < 4; ++i) {
        int row = mt * 16 + quad * 4 + i;
        int node = n0 + row;
        if (node < NNODES)
          out[(size_t)node * NDIM + col] = acc[mt][nt][i] + bb;
      }
    }
  }
}

extern "C" void kernel_launch(void* const* d_in, const int* in_sizes, int n_in,
                              void* d_out, int out_size, void* d_ws, size_t ws_size,
                              hipStream_t stream) {
  const float* node_feats = (const float*)d_in[0];
  const float* edge_feats = (const float*)d_in[1];
  const float* msg_w1 = (const float*)d_in[2];
  const float* msg_b1 = (const float*)d_in[3];
  const float* msg_w2 = (const float*)d_in[4];
  const float* msg_b2 = (const float*)d_in[5];
  const float* upd_w1 = (const float*)d_in[6];
  const float* upd_b1 = (const float*)d_in[7];
  const float* upd_w2 = (const float*)d_in[8];
  const float* upd_b2 = (const float*)d_in[9];
  const int* eidx = (const int*)d_in[10];

  // ws layout (16B-aligned sections)
  float* hagg   = (float*)d_ws;                        // N*128 f32
  int* cnt      = (int*)(hagg + (size_t)NNODES * NDIM);// N (zeroed with hagg)
  int* row_ptr  = cnt + NNODES;                        // N
  int* bsum     = row_ptr + NNODES;                    // 256
  int* bscan    = bsum + 256;                          // 256
  int4* s_edges = (int4*)(bscan + 256);                // E int4
  short* w1t    = (short*)(s_edges + NEDGES);          // 128*K1 bf16
  short* w2t    = w1t + 128 * K1;
  short* u1t    = w2t + 128 * 128;
  short* u2t    = u1t + 128 * K2;

  hipMemsetAsync(d_ws, 0, (size_t)(NNODES * NDIM + NNODES) * sizeof(float), stream);

  wt_kernel<<<(K1 * 128) / 256, 256, 0, stream>>>(msg_w1, w1t, K1);
  wt_kernel<<<(128 * 128) / 256, 256, 0, stream>>>(msg_w2, w2t, 128);
  wt_kernel<<<(K2 * 128) / 256, 256, 0, stream>>>(upd_w1, u1t, K2);
  wt_kernel<<<(128 * 128) / 256, 256, 0, stream>>>(upd_w2, u2t, 128);

  hist_kernel<<<NEDGES / 256, 256, 0, stream>>>(eidx, cnt);
  scan_reduce_kernel<<<NB, 256, 0, stream>>>(cnt, bsum);
  scan_top_kernel<<<1, 256, 0, stream>>>(bsum, bscan);
  scan_down_kernel<<<NB, 256, 0, stream>>>(cnt, bscan, row_ptr);
  permute_kernel<<<NEDGES / 256, 256, 0, stream>>>(eidx, row_ptr, cnt, s_edges);

  edge_kernel<<<NEDGES / 64, 256, 0, stream>>>(node_feats, edge_feats, s_edges,
                                               w1t, msg_b1, hagg);
  node_kernel<<<(NNODES + 63) / 64, 256, 0, stream>>>(node_feats, hagg, cnt,
                                                      w2t, msg_b2, u1t, upd_b1,
                                                      u2t, upd_b2, (float*)d_out);
}

// Round 3
// 541.107 us; speedup vs baseline: 1.2340x; 1.0435x over previous
//
#include <hip/hip_runtime.h>
#include <hip/hip_bf16.h>

#define NNODES 50000
#define NEDGES 800000
#define NDIM   128
#define EDIM   64
#define K1     192   // NDIM + EDIM
#define K2     256   // 2*NDIM
#define NB     196   // ceil(NNODES/256) scan blocks

#define KP1 200      // LDS k-stride (shorts) for K=192 tile
#define KPA 136      // LDS k-stride for K=128
#define KPU 264      // LDS k-stride for K=256
#define MSTR 132     // LDS col-stride (floats) for 32-row message tile

typedef __attribute__((ext_vector_type(8))) short bf16x8;
typedef __attribute__((ext_vector_type(4))) short bf16x4;
typedef __attribute__((ext_vector_type(4))) float f32x4;

__device__ inline short f2bf(float f) {
  union { float f; unsigned u; } v; v.f = f;
  unsigned r = v.u + 0x7FFFu + ((v.u >> 16) & 1u);   // round-to-nearest-even
  return (short)(r >> 16);
}

__device__ inline bf16x4 pack4(float4 v) {
  bf16x4 p;
  p[0] = f2bf(v.x); p[1] = f2bf(v.y); p[2] = f2bf(v.z); p[3] = f2bf(v.w);
  return p;
}

// fp32 -> bf16 streaming convert (float4 per thread)
__global__ __launch_bounds__(256) void cvt_kernel(const float* __restrict__ src,
                                                  short* __restrict__ dst, int n) {
  int i = (blockIdx.x * 256 + threadIdx.x) * 4;
  if (i < n) {
    float4 v = *(const float4*)(src + i);
    *(bf16x4*)(dst + i) = pack4(v);
  }
}

// Transpose+convert fp32 weight [K][128] -> bf16 [n][K]
__global__ __launch_bounds__(256) void wt_kernel(const float* __restrict__ w,
                                                 short* __restrict__ wt, int K) {
  int i = blockIdx.x * 256 + threadIdx.x;
  if (i < K * NDIM) {
    int k = i >> 7;
    int n = i & 127;
    wt[n * K + k] = f2bf(w[i]);
  }
}

// ---- counting-sort pipeline: sort edges by src ----
__global__ __launch_bounds__(256) void hist_kernel(const int* __restrict__ eidx,
                                                   int* __restrict__ cnt) {
  int i = blockIdx.x * 256 + threadIdx.x;
  if (i < NEDGES) atomicAdd(&cnt[eidx[i]], 1);
}

__global__ __launch_bounds__(256) void scan_reduce_kernel(const int* __restrict__ cnt,
                                                          int* __restrict__ bsum) {
  __shared__ int sh[256];
  int tid = threadIdx.x;
  int i = blockIdx.x * 256 + tid;
  sh[tid] = (i < NNODES) ? cnt[i] : 0;
  __syncthreads();
#pragma unroll
  for (int off = 128; off > 0; off >>= 1) {
    if (tid < off) sh[tid] += sh[tid + off];
    __syncthreads();
  }
  if (tid == 0) bsum[blockIdx.x] = sh[0];
}

__global__ __launch_bounds__(256) void scan_top_kernel(const int* __restrict__ bsum,
                                                       int* __restrict__ bscan) {
  __shared__ int sh[256];
  int tid = threadIdx.x;
  int v = (tid < NB) ? bsum[tid] : 0;
  sh[tid] = v;
  __syncthreads();
#pragma unroll
  for (int off = 1; off < 256; off <<= 1) {
    int t = (tid >= off) ? sh[tid - off] : 0;
    __syncthreads();
    sh[tid] += t;
    __syncthreads();
  }
  bscan[tid] = sh[tid] - v;   // exclusive
}

__global__ __launch_bounds__(256) void scan_down_kernel(int* __restrict__ cnt,
                                                        const int* __restrict__ bscan,
                                                        int* __restrict__ row_ptr) {
  __shared__ int sh[256];
  int tid = threadIdx.x;
  int i = blockIdx.x * 256 + tid;
  int v = (i < NNODES) ? cnt[i] : 0;
  sh[tid] = v;
  __syncthreads();
#pragma unroll
  for (int off = 1; off < 256; off <<= 1) {
    int t = (tid >= off) ? sh[tid - off] : 0;
    __syncthreads();
    sh[tid] += t;
    __syncthreads();
  }
  if (i < NNODES) {
    row_ptr[i] = bscan[blockIdx.x] + (sh[tid] - v);
    cnt[i] = 0;                 // reset: becomes ticket counter, ends as degree
  }
}

__global__ __launch_bounds__(256) void permute_kernel(const int* __restrict__ eidx,
                                                      const int* __restrict__ row_ptr,
                                                      int* __restrict__ cnt,
                                                      int4* __restrict__ s_edges) {
  int e = blockIdx.x * 256 + threadIdx.x;
  if (e < NEDGES) {
    int s = eidx[e];
    int d = eidx[NEDGES + e];
    int pos = row_ptr[s] + atomicAdd(&cnt[s], 1);
    s_edges[pos] = make_int4(s, d, e, 0);
  }
}

// ---- edge kernel: h = lrelu(concat(nf_bf[dst], ef)@W1 + b1);
//      run-aggregated atomic scatter, 32-row halves, LDS 26.4KB -> 6 blocks/CU ----
__global__ __launch_bounds__(256, 6) void edge_kernel(const short* __restrict__ nf_bf,
                                                      const float* __restrict__ edge_feats,
                                                      const int4* __restrict__ s_edges,
                                                      const short* __restrict__ w1t,
                                                      const float* __restrict__ b1,
                                                      float* __restrict__ hagg) {
  __shared__ __align__(16) char SH[64 * KP1 * 2];    // 25600 B: X tile, then M (32x132 fp32)
  __shared__ int srcs[64];
  __shared__ int dsts[64];
  __shared__ int eids[64];

  short* X = (short*)SH;     // bf16 [64][KP1]
  float* M = (float*)SH;     // fp32 [32][MSTR] = 16896 B (aliased after X dead)

  const int tid = threadIdx.x;
  const int e0 = blockIdx.x * 64;

  if (tid < 64) {
    int4 v = s_edges[e0 + tid];
    srcs[tid] = v.x;
    dsts[tid] = v.y;
    eids[tid] = v.z;
  }
  __syncthreads();

  // Stage: 4 threads/row; nf_bf[dst] (plain 16B copies) -> cols 0:128,
  //        edge_feats[eid] fp32->bf16 -> cols 128:192
  {
    int r = tid >> 2, q = tid & 3;
    const bf16x8* np = (const bf16x8*)(nf_bf + (size_t)dsts[r] * NDIM) + q * 4;
    const float4* ep = (const float4*)(edge_feats + (size_t)eids[r] * EDIM) + q * 4;
    short* dpn = X + r * KP1 + q * 32;
    short* dpe = X + r * KP1 + NDIM + q * 16;
#pragma unroll
    for (int j = 0; j < 4; ++j) *(bf16x8*)(dpn + j * 8) = np[j];
#pragma unroll
    for (int j = 0; j < 4; ++j) *(bf16x4*)(dpe + j * 4) = pack4(ep[j]);
  }
  __syncthreads();

  const int lane = tid & 63;
  const int wv = tid >> 6;
  const int m16 = lane & 15;
  const int quad = lane >> 4;

  f32x4 acc[4][2];
#pragma unroll
  for (int mt = 0; mt < 4; ++mt)
#pragma unroll
    for (int nt = 0; nt < 2; ++nt)
      acc[mt][nt] = (f32x4){0.f, 0.f, 0.f, 0.f};

#pragma unroll
  for (int ks = 0; ks < 6; ++ks) {
    const int k0 = ks * 32 + quad * 8;
    bf16x8 b[2];
#pragma unroll
    for (int nt = 0; nt < 2; ++nt) {
      int n = wv * 32 + nt * 16 + m16;
      b[nt] = *(const bf16x8*)(w1t + n * K1 + k0);
    }
#pragma unroll
    for (int mt = 0; mt < 4; ++mt) {
      bf16x8 a = *(const bf16x8*)(X + (mt * 16 + m16) * KP1 + k0);
#pragma unroll
      for (int nt = 0; nt < 2; ++nt)
        acc[mt][nt] = __builtin_amdgcn_mfma_f32_16x16x32_bf16(a, b[nt], acc[mt][nt], 0, 0, 0);
    }
  }
  __syncthreads();   // all X reads done before M overwrites it

  // Two 32-row halves: epilogue -> M, then 256-thread run-aggregated scatter
#pragma unroll
  for (int h = 0; h < 2; ++h) {
#pragma unroll
    for (int nt = 0; nt < 2; ++nt) {
      int col = wv * 32 + nt * 16 + m16;
      float bb = b1[col];
#pragma unroll
      for (int mt2 = 0; mt2 < 2; ++mt2) {
        int mt = h * 2 + mt2;
#pragma unroll
        for (int i = 0; i < 4; ++i) {
          float v = acc[mt][nt][i] + bb;
          v = v >= 0.f ? v : 0.2f * v;
          int lr = mt2 * 16 + quad * 4 + i;
          M[lr * MSTR + col] = v;
        }
      }
    }
    __syncthreads();
    {
      const int c = tid & 127;
      const int lr0 = (tid >> 7) * 16;      // 16-row strip
      const int g0 = h * 32 + lr0;
      float a = M[lr0 * MSTR + c];
      int prev = srcs[g0];
#pragma unroll 4
      for (int r = 1; r < 16; ++r) {
        int s = srcs[g0 + r];
        float v = M[(lr0 + r) * MSTR + c];
        if (s != prev) {
          atomicAdd(&hagg[(size_t)prev * NDIM + c], a);
          a = v;
          prev = s;
        } else {
          a += v;
        }
      }
      atomicAdd(&hagg[(size_t)prev * NDIM + c], a);
    }
    if (h == 0) __syncthreads();   // M reused by second half
  }
}

// ---- node kernel: agg = hagg@W2 + deg*b2; out = lrelu(concat(x,agg)@U1+ub1)@U2+ub2 ----
__global__ __launch_bounds__(256) void node_kernel(const short* __restrict__ nf_bf,
                                                   const float* __restrict__ hagg,
                                                   const int* __restrict__ degc,
                                                   const short* __restrict__ w2t,
                                                   const float* __restrict__ b2,
                                                   const short* __restrict__ u1t,
                                                   const float* __restrict__ ub1,
                                                   const short* __restrict__ u2t,
                                                   const float* __restrict__ ub2,
                                                   float* __restrict__ out) {
  __shared__ __align__(16) short AGH[64 * KPA];   // phase1: hagg tile; phase3: h2 tile
  __shared__ __align__(16) short XU[64 * KPU];    // concat(x, agg) tile
  __shared__ float degs[64];

  const int tid = threadIdx.x;
  const int n0 = blockIdx.x * 64;

  if (tid < 64) {
    int node = n0 + tid;
    degs[tid] = (node < NNODES) ? (float)degc[node] : 0.f;
  }
  {
    int r = tid >> 2, q = tid & 3;
    int node = n0 + r; if (node >= NNODES) node = NNODES - 1;
    const float4* hp = (const float4*)(hagg + (size_t)node * NDIM) + q * 8;
    const bf16x8* xp = (const bf16x8*)(nf_bf + (size_t)node * NDIM) + q * 4;
    short* ap = AGH + r * KPA + q * 32;
    short* xq = XU + r * KPU + q * 32;
#pragma unroll
    for (int j = 0; j < 8; ++j) *(bf16x4*)(ap + j * 4) = pack4(hp[j]);
#pragma unroll
    for (int j = 0; j < 4; ++j) *(bf16x8*)(xq + j * 8) = xp[j];
  }
  __syncthreads();

  const int lane = tid & 63;
  const int wv = tid >> 6;
  const int m16 = lane & 15;
  const int quad = lane >> 4;

  f32x4 acc[4][2];

  // ---- GEMM-a: agg = AGH @ W2 (K=128) ----
#pragma unroll
  for (int mt = 0; mt < 4; ++mt)
#pragma unroll
    for (int nt = 0; nt < 2; ++nt)
      acc[mt][nt] = (f32x4){0.f, 0.f, 0.f, 0.f};
#pragma unroll
  for (int ks = 0; ks < 4; ++ks) {
    const int k0 = ks * 32 + quad * 8;
    bf16x8 b[2];
#pragma unroll
    for (int nt = 0; nt < 2; ++nt) {
      int n = wv * 32 + nt * 16 + m16;
      b[nt] = *(const bf16x8*)(w2t + n * NDIM + k0);
    }
#pragma unroll
    for (int mt = 0; mt < 4; ++mt) {
      bf16x8 a = *(const bf16x8*)(AGH + (mt * 16 + m16) * KPA + k0);
#pragma unroll
      for (int nt = 0; nt < 2; ++nt)
        acc[mt][nt] = __builtin_amdgcn_mfma_f32_16x16x32_bf16(a, b[nt], acc[mt][nt], 0, 0, 0);
    }
  }
#pragma unroll
  for (int nt = 0; nt < 2; ++nt) {
    int col = wv * 32 + nt * 16 + m16;
    float bb = b2[col];
#pragma unroll
    for (int mt = 0; mt < 4; ++mt) {
#pragma unroll
      for (int i = 0; i < 4; ++i) {
        int row = mt * 16 + quad * 4 + i;
        float v = acc[mt][nt][i] + degs[row] * bb;
        XU[row * KPU + NDIM + col] = f2bf(v);
      }
    }
  }
  __syncthreads();

  // ---- GEMM-b: t = XU @ U1 (K=256), lrelu -> AGH ----
#pragma unroll
  for (int mt = 0; mt < 4; ++mt)
#pragma unroll
    for (int nt = 0; nt < 2; ++nt)
      acc[mt][nt] = (f32x4){0.f, 0.f, 0.f, 0.f};
#pragma unroll
  for (int ks = 0; ks < 8; ++ks) {
    const int k0 = ks * 32 + quad * 8;
    bf16x8 b[2];
#pragma unroll
    for (int nt = 0; nt < 2; ++nt) {
      int n = wv * 32 + nt * 16 + m16;
      b[nt] = *(const bf16x8*)(u1t + n * K2 + k0);
    }
#pragma unroll
    for (int mt = 0; mt < 4; ++mt) {
      bf16x8 a = *(const bf16x8*)(XU + (mt * 16 + m16) * KPU + k0);
#pragma unroll
      for (int nt = 0; nt < 2; ++nt)
        acc[mt][nt] = __builtin_amdgcn_mfma_f32_16x16x32_bf16(a, b[nt], acc[mt][nt], 0, 0, 0);
    }
  }
  __syncthreads();
#pragma unroll
  for (int nt = 0; nt < 2; ++nt) {
    int col = wv * 32 + nt * 16 + m16;
    float bb = ub1[col];
#pragma unroll
    for (int mt = 0; mt < 4; ++mt) {
#pragma unroll
      for (int i = 0; i < 4; ++i) {
        int row = mt * 16 + quad * 4 + i;
        float v = acc[mt][nt][i] + bb;
        v = v >= 0.f ? v : 0.2f * v;
        AGH[row * KPA + col] = f2bf(v);
      }
    }
  }
  __syncthreads();

  // ---- GEMM-c: out = h2 @ U2 (K=128) + ub2 ----
#pragma unroll
  for (int mt = 0; mt < 4; ++mt)
#pragma unroll
    for (int nt = 0; nt < 2; ++nt)
      acc[mt][nt] = (f32x4){0.f, 0.f, 0.f, 0.f};
#pragma unroll
  for (int ks = 0; ks < 4; ++ks) {
    const int k0 = ks * 32 + quad * 8;
    bf16x8 b[2];
#pragma unroll
    for (int nt = 0; nt < 2; ++nt) {
      int n = wv * 32 + nt * 16 + m16;
      b[nt] = *(const bf16x8*)(u2t + n * NDIM + k0);
    }
#pragma unroll
    for (int mt = 0; mt < 4; ++mt) {
      bf16x8 a = *(const bf16x8*)(AGH + (mt * 16 + m16) * KPA + k0);
#pragma unroll
      for (int nt = 0; nt < 2; ++nt)
        acc[mt][nt] = __builtin_amdgcn_mfma_f32_16x16x32_bf16(a, b[nt], acc[mt][nt], 0, 0, 0);
    }
  }
#pragma unroll
  for (int nt = 0; nt < 2; ++nt) {
    int col = wv * 32 + nt * 16 + m16;
    float bb = ub2[col];
#pragma unroll
    for (int mt = 0; mt < 4; ++mt) {
#pragma unroll
      for (int i = 0; i < 4; ++i) {
        int row = mt * 16 + quad * 4 + i;
        int node = n0 + row;
        if (node < NNODES)
          out[(size_t)node * NDIM + col] = acc[mt][nt][i] + bb;
      }
    }
  }
}

extern "C" void kernel_launch(void* const* d_in, const int* in_sizes, int n_in,
                              void* d_out, int out_size, void* d_ws, size_t ws_size,
                              hipStream_t stream) {
  const float* node_feats = (const float*)d_in[0];
  const float* edge_feats = (const float*)d_in[1];
  const float* msg_w1 = (const float*)d_in[2];
  const float* msg_b1 = (const float*)d_in[3];
  const float* msg_w2 = (const float*)d_in[4];
  const float* msg_b2 = (const float*)d_in[5];
  const float* upd_w1 = (const float*)d_in[6];
  const float* upd_b1 = (const float*)d_in[7];
  const float* upd_w2 = (const float*)d_in[8];
  const float* upd_b2 = (const float*)d_in[9];
  const int* eidx = (const int*)d_in[10];

  // ws layout (16B-aligned sections)
  float* hagg   = (float*)d_ws;                        // N*128 f32
  int* cnt      = (int*)(hagg + (size_t)NNODES * NDIM);// N (zeroed with hagg)
  int* row_ptr  = cnt + NNODES;                        // N
  int* bsum     = row_ptr + NNODES;                    // 256
  int* bscan    = bsum + 256;                          // 256
  int4* s_edges = (int4*)(bscan + 256);                // E int4
  short* w1t    = (short*)(s_edges + NEDGES);          // 128*K1 bf16
  short* w2t    = w1t + 128 * K1;
  short* u1t    = w2t + 128 * 128;
  short* u2t    = u1t + 128 * K2;
  short* nf_bf  = u2t + 128 * 128;                     // N*128 bf16

  hipMemsetAsync(d_ws, 0, (size_t)(NNODES * NDIM + NNODES) * sizeof(float), stream);

  cvt_kernel<<<(NNODES * NDIM / 4 + 255) / 256, 256, 0, stream>>>(node_feats, nf_bf,
                                                                  NNODES * NDIM);
  wt_kernel<<<(K1 * 128) / 256, 256, 0, stream>>>(msg_w1, w1t, K1);
  wt_kernel<<<(128 * 128) / 256, 256, 0, stream>>>(msg_w2, w2t, 128);
  wt_kernel<<<(K2 * 128) / 256, 256, 0, stream>>>(upd_w1, u1t, K2);
  wt_kernel<<<(128 * 128) / 256, 256, 0, stream>>>(upd_w2, u2t, 128);

  hist_kernel<<<NEDGES / 256, 256, 0, stream>>>(eidx, cnt);
  scan_reduce_kernel<<<NB, 256, 0, stream>>>(cnt, bsum);
  scan_top_kernel<<<1, 256, 0, stream>>>(bsum, bscan);
  scan_down_kernel<<<NB, 256, 0, stream>>>(cnt, bscan, row_ptr);
  permute_kernel<<<NEDGES / 256, 256, 0, stream>>>(eidx, row_ptr, cnt, s_edges);

  edge_kernel<<<NEDGES / 64, 256, 0, stream>>>(nf_bf, edge_feats, s_edges,
                                               w1t, msg_b1, hagg);
  node_kernel<<<(NNODES + 63) / 64, 256, 0, stream>>>(nf_bf, hagg, cnt,
                                                      w2t, msg_b2, u1t, upd_b1,
                                                      u2t, upd_b2, (float*)d_out);
}